// Round 14
// baseline (195.701 us; speedup 1.0000x reference)
//
#include <hip/hip_runtime.h>
#include <math.h>

// N=100000 nodes, E=1000000 edges, D_IN=64, D_MODEL=64, H=4 x D=16.
// Packed node layout: per node, 16 chunks of 16 B; chunk c = bytes [16c,16c+16)
//   = { q[4c..4c+3] fp16 (8 B) | v[4c..4c+3] fp16 (8 B) }. Row = 256 B.

typedef _Float16 h2 __attribute__((ext_vector_type(2)));
typedef _Float16 half8 __attribute__((ext_vector_type(8)));
typedef float floatx4 __attribute__((ext_vector_type(4)));

#define SP_ROW 136  // fp16 per LDS row (272 B): +8 pad breaks pow-2 bank stride
#define SW_ROW 72   // fp16 per sW row (144 B = 9x16: 16-B aligned b128 reads)

// ---------------------------------------------------------------------------
// Kernel 1: MFMA fp16 projection -> packed fp16 q|v rows. Self-contained
// (stages Wqk|Wv transposed-cast into LDS; one __syncthreads). Tail blocks
// [PB, PB+RB) do the CSR rowptr binary search.  (UNCHANGED from r13 — control)
__global__ __launch_bounds__(256) void mhga_proj(
    const float* __restrict__ X,
    const float* __restrict__ Wqk, const float* __restrict__ Wv,
    const float* __restrict__ bqk, const float* __restrict__ bv,
    unsigned char* __restrict__ packed,
    const int* __restrict__ receivers, int* __restrict__ row_ptr,
    int N, int E, int PB)
{
    if ((int)blockIdx.x >= PB) {
        const int n = (blockIdx.x - PB) * 256 + threadIdx.x;
        if (n > N) return;
        int lo = 0, hi = E;
        while (lo < hi) {
            const int mid = (lo + hi) >> 1;
            if (receivers[mid] < n) lo = mid + 1; else hi = mid;
        }
        row_ptr[n] = lo;
        return;
    }

    __shared__ __align__(16) _Float16 sP[64 * SP_ROW];   // 17408 B repack tile
    __shared__ __align__(16) _Float16 sW[128 * SW_ROW];  // 18432 B weight tile
    const int t = threadIdx.x;
    const int w = t >> 6, lane = t & 63;
    const int ln = lane & 15, quad = lane >> 4;
    const int m0 = blockIdx.x * 64;

    // Stage sW[m][k] = fp16 of (m<64 ? Wqk[k][m] : Wv[k][m-64]).
    for (int i = t; i < 8192; i += 256) {
        const int hf = i >> 12;          // 0: Wqk, 1: Wv
        const int j = i & 4095;          // j = k*64 + m'
        const int k = j >> 6, mp = j & 63;
        const float wv = hf ? Wv[j] : Wqk[j];
        sW[(hf * 64 + mp) * SW_ROW + k] = (_Float16)wv;
    }

    // A fragments: A[m=ln][k=quad*8+j], k-halves 0 / 32. Direct f32 loads.
    const int arow = min(m0 + w * 16 + ln, N - 1);
    const float* xr = X + (size_t)arow * 64;
    const float4 xa = *(const float4*)(xr + quad * 8);
    const float4 xb = *(const float4*)(xr + quad * 8 + 4);
    const float4 xc = *(const float4*)(xr + 32 + quad * 8);
    const float4 xd = *(const float4*)(xr + 32 + quad * 8 + 4);
    const half8 a0 = { (_Float16)xa.x, (_Float16)xa.y, (_Float16)xa.z,
                       (_Float16)xa.w, (_Float16)xb.x, (_Float16)xb.y,
                       (_Float16)xb.z, (_Float16)xb.w };
    const half8 a1 = { (_Float16)xc.x, (_Float16)xc.y, (_Float16)xc.z,
                       (_Float16)xc.w, (_Float16)xd.x, (_Float16)xd.y,
                       (_Float16)xd.z, (_Float16)xd.w };

    __syncthreads();   // sW visible to all waves

    // 8 output tiles: B[k][n], lane&15 = n-within-tile, k = quad*8+j.
    floatx4 acc[8];
#pragma unroll
    for (int tt = 0; tt < 8; ++tt) {
        const _Float16* wrow = sW + (tt * 16 + ln) * SW_ROW;
        const half8 b0 = *(const half8*)(wrow + quad * 8);
        const half8 b1 = *(const half8*)(wrow + 32 + quad * 8);
        floatx4 c = {0.f, 0.f, 0.f, 0.f};
        c = __builtin_amdgcn_mfma_f32_16x16x32_f16(a0, b0, c, 0, 0, 0);
        c = __builtin_amdgcn_mfma_f32_16x16x32_f16(a1, b1, c, 0, 0, 0);
        acc[tt] = c;
    }

    // Repack: D row = quad*4+reg, col j = tt*16+ln. q col j -> fp16 idx
    // (j>>2)*8 + (j&3); v col j -> (j>>2)*8 + 4 + (j&3).
#pragma unroll
    for (int tt = 0; tt < 8; ++tt) {
        const float bt = (tt < 4) ? bqk[tt * 16 + ln] : bv[(tt - 4) * 16 + ln];
        const int j = (tt & 3) * 16 + ln;
        const int fidx = (j >> 2) * 8 + ((tt < 4) ? 0 : 4) + (j & 3);
#pragma unroll
        for (int r = 0; r < 4; ++r) {
            const int lrow = w * 16 + quad * 4 + r;
            sP[lrow * SP_ROW + fidx] = (_Float16)(acc[tt][r] + bt);
        }
    }

    // Wave-local coalesced copy (no barrier; same-wave in-order DS).
    const int crow = w * 16 + (lane >> 2);
    const int grow = m0 + crow;
    if (grow < N) {
        const _Float16* src = sP + crow * SP_ROW + (lane & 3) * 32;
        unsigned char* dst = packed + (size_t)grow * 256 + (lane & 3) * 64;
#pragma unroll
        for (int c = 0; c < 4; ++c)
            *(uint4*)(dst + c * 16) = *(const uint4*)(src + c * 8);
    }
}

// ---------------------------------------------------------------------------
// Kernel 2: fused attention + per-super-lap MFMA out-projection (round-14).
// r13's OccupancyPercent=40% on a 100%-resident grid exposed STRAGGLER WAVES:
// node-balanced partitions leave per-wave edge totals Poisson-distributed
// (sigma/mu ~28%; max over 8192 waves ~2x mean -> wall = 2x mean work).
// Fix: EDGE-BALANCED static partition. Each wave binary-searches rowptr
// (L2-hot, once) for the contiguous node range holding an equal share of
// cost c(n) = rowptr[n] + 8n (8 ~ per-node fixed overhead in edge-equiv).
// Residual imbalance <= ~1 node. No atomics, no new sync; per-node
// arithmetic is bit-identical (pure re-scheduling). sC epilogue flushes
// every <=16 contiguous nodes (super-lap); e1 of node n recycles as e0 of
// node n+1 (-1 dependent load/lap). Hot-loop body byte-identical to r13.
__global__ __launch_bounds__(256) void mhga_attn(
    const unsigned char* __restrict__ packed,
    const int* __restrict__ senders, const int* __restrict__ row_ptr,
    const float* __restrict__ Wout, const float* __restrict__ bout,
    float* __restrict__ out, float* __restrict__ attn_out,
    int N, int E, int NW)
{
    __shared__ float sAtt[4][256];                    // p stage (4 KB)
    __shared__ __align__(16) _Float16 sC[4][16][76];  // ctx tiles (9728 B)
    const int t = threadIdx.x;
    const int wave = t >> 6, lane = t & 63;
    const int g = lane >> 4, tl = lane & 15;   // edge-group, channel-lane

    const int W = blockIdx.x * 4 + wave;              // global wave id

    // ---- edge-balanced range [n0, n1): lower_bound of c(n)=rowptr[n]+8n ----
    const long long Ctot = (long long)E + 8LL * N;
    long long tgt0 = ((long long)W * Ctot) / NW;
    long long tgt1 = ((long long)(W + 1) * Ctot) / NW;
    int n0, n1;
    {
        int lo = 0, hi = N;
        while (lo < hi) {
            const int mid = (lo + hi) >> 1;
            if ((long long)row_ptr[mid] + 8LL * mid < tgt0) lo = mid + 1;
            else hi = mid;
        }
        n0 = lo;
        hi = N;                       // c monotone: n1 >= n0
        while (lo < hi) {
            const int mid = (lo + hi) >> 1;
            if ((long long)row_ptr[mid] + 8LL * mid < tgt1) lo = mid + 1;
            else hi = mid;
        }
        n1 = (W + 1 == NW) ? N : lo;
    }

    int e_run = (n0 < n1) ? row_ptr[n0] : 0;

    for (int ns = n0; ns < n1; ns += 16) {            // super-laps of <=16 nodes
        const int cc = min(16, n1 - ns);
        for (int i = 0; i < cc; ++i) {
            const int n = ns + i;
            const int e0 = e_run;
            const int e1 = row_ptr[n + 1];
            e_run = e1;
            const int cnt = e1 - e0;

            float l = 0.f;
            float4 ctx = make_float4(0.f, 0.f, 0.f, 0.f);
            const uint2 qpk =
                *(const uint2*)(packed + (size_t)n * 256 + tl * 16);
            const h2 q0 = __builtin_bit_cast(h2, qpk.x);
            const h2 q1 = __builtin_bit_cast(h2, qpk.y);

            if (cnt <= 64) {
                // ---- hot path: 2-deep pipelined gathers, p staged in LDS ----
                int sid = 0;
                if (e0 + lane < e1) sid = senders[e0 + lane];   // coalesced
                const int iters = (cnt + 3) >> 2;
                const int s0 = __shfl(sid, g, 64);
                uint4 pk = *(const uint4*)(packed + (size_t)s0 * 256 + tl * 16);
                for (int it = 0; it < iters; ++it) {
                    uint4 pkn = pk;
                    if (it + 1 < iters) {                // wave-uniform branch
                        const int sn = __shfl(sid, (it + 1) * 4 + g, 64);
                        pkn = *(const uint4*)(packed +
                                              (size_t)sn * 256 + tl * 16);
                    }
                    const int idx = it * 4 + g;          // this group's edge
                    const h2 k0 = __builtin_bit_cast(h2, pk.x);
                    const h2 k1 = __builtin_bit_cast(h2, pk.y);
                    const h2 v0 = __builtin_bit_cast(h2, pk.z);
                    const h2 v1 = __builtin_bit_cast(h2, pk.w);
                    float d = __builtin_amdgcn_fdot2(q0, k0, 0.f, false);
                    d = __builtin_amdgcn_fdot2(q1, k1, d, false);
                    d += __shfl_xor(d, 1, 64);          // head-group reduce
                    d += __shfl_xor(d, 2, 64);
                    float p = __expf(d);
                    p = (idx < cnt) ? p : 0.f;          // cndmask, no branch
                    if ((tl & 3) == 0)
                        sAtt[wave][idx * 4 + (tl >> 2)] = p;   // conflict-free
                    l += p;
                    ctx.x = fmaf(p, (float)v0.x, ctx.x);
                    ctx.y = fmaf(p, (float)v0.y, ctx.y);
                    ctx.z = fmaf(p, (float)v1.x, ctx.z);
                    ctx.w = fmaf(p, (float)v1.y, ctx.w);
                    pk = pkn;
                }
            } else {
                // ---- rare fallback: raw p -> attn_out, normalize in place ----
                for (int base = e0; base < e1; base += 64) {
                    const int c2 = min(64, e1 - base);
                    int sid2 = 0;
                    if (base + lane < e1) sid2 = senders[base + lane];
                    const int it2 = (c2 + 3) >> 2;
                    for (int ii = 0; ii < it2; ++ii) {
                        const int idx = ii * 4 + g;
                        const int s = __shfl(sid2, idx, 64);
                        if (idx < c2) {
                            const uint4 pk = *(const uint4*)(
                                packed + (size_t)s * 256 + tl * 16);
                            const h2 k0 = __builtin_bit_cast(h2, pk.x);
                            const h2 k1 = __builtin_bit_cast(h2, pk.y);
                            const h2 v0 = __builtin_bit_cast(h2, pk.z);
                            const h2 v1 = __builtin_bit_cast(h2, pk.w);
                            float d = __builtin_amdgcn_fdot2(q0, k0, 0.f, false);
                            d = __builtin_amdgcn_fdot2(q1, k1, d, false);
                            d += __shfl_xor(d, 1, 64);
                            d += __shfl_xor(d, 2, 64);
                            const float p = __expf(d);
                            if ((tl & 3) == 0)
                                attn_out[(size_t)(base + idx) * 4 + (tl >> 2)] = p;
                            l += p;
                            ctx.x = fmaf(p, (float)v0.x, ctx.x);
                            ctx.y = fmaf(p, (float)v0.y, ctx.y);
                            ctx.z = fmaf(p, (float)v1.x, ctx.z);
                            ctx.w = fmaf(p, (float)v1.y, ctx.w);
                        }
                    }
                }
            }

            // Sum the 4 edge-group partials (butterfly -> all lanes merged).
#pragma unroll
            for (int mask = 16; mask <= 32; mask <<= 1) {
                l     += __shfl_xor(l, mask, 64);
                ctx.x += __shfl_xor(ctx.x, mask, 64);
                ctx.y += __shfl_xor(ctx.y, mask, 64);
                ctx.z += __shfl_xor(ctx.z, mask, 64);
                ctx.w += __shfl_xor(ctx.w, mask, 64);
            }
            const float inv = (l > 0.f) ? (1.f / l) : 0.f;   // head = tl>>2

            // Pass B: attn = p / l[head], head = f&3 = lane&3 (stride 64).
            const float lh = __shfl(l, (lane & 3) << 2, 64);
            const float invl = (lh > 0.f) ? (1.f / lh) : 0.f;
            if (cnt <= 64) {
                const int cnt4 = cnt * 4;
                for (int f = lane; f < cnt4; f += 64)
                    attn_out[e0 * 4 + f] = sAtt[wave][f] * invl;  // wave LDS
            } else {
                __builtin_amdgcn_s_waitcnt(0x0F70);  // vmcnt(0): drain stores
                volatile const float* vp = attn_out; // L1-bypass
                for (int f = e0 * 4 + lane; f < e1 * 4; f += 64)
                    attn_out[f] = vp[f] * invl;
            }

            // Normalized ctx -> fp16 LDS tile row i (g==0 lanes, 16 x 8 B).
            if (g == 0) {
                const h2 c01 = { (_Float16)(ctx.x * inv),
                                 (_Float16)(ctx.y * inv) };
                const h2 c23 = { (_Float16)(ctx.z * inv),
                                 (_Float16)(ctx.w * inv) };
                uint2 pc;
                pc.x = __builtin_bit_cast(unsigned int, c01);
                pc.y = __builtin_bit_cast(unsigned int, c23);
                *(uint2*)(&sC[wave][i][tl * 4]) = pc;
            }
        }

        // ---- per-super-lap MFMA out-projection: rows ns..ns+cc-1 ----
        // A[m=tl][k=g*8+j] from sC (same-wave in-order DS: no barrier);
        // rows >= cc are garbage but D-rows are independent and unstored.
        // B[k][n] built directly from Wout (L2-hot scalar loads + fp16 cast).
        const half8 a0 = *(const half8*)(&sC[wave][tl][g * 8]);
        const half8 a1 = *(const half8*)(&sC[wave][tl][32 + g * 8]);
#pragma unroll
        for (int tt = 0; tt < 4; ++tt) {
            half8 b0, b1;
#pragma unroll
            for (int j = 0; j < 8; ++j) {
                b0[j] = (_Float16)Wout[(g * 8 + j) * 64 + tt * 16 + tl];
                b1[j] = (_Float16)Wout[(32 + g * 8 + j) * 64 + tt * 16 + tl];
            }
            floatx4 c = {0.f, 0.f, 0.f, 0.f};
            c = __builtin_amdgcn_mfma_f32_16x16x32_f16(a0, b0, c, 0, 0, 0);
            c = __builtin_amdgcn_mfma_f32_16x16x32_f16(a1, b1, c, 0, 0, 0);
            const float bt = bout[tt * 16 + tl];
#pragma unroll
            for (int r = 0; r < 4; ++r) {
                const int lrow = g * 4 + r;
                if (lrow < cc)
                    out[(size_t)(ns + lrow) * 64 + tt * 16 + tl] = c[r] + bt;
            }
        }
    }
}

// ---------------------------------------------------------------------------
extern "C" void kernel_launch(void* const* d_in, const int* in_sizes, int n_in,
                              void* d_out, int out_size, void* d_ws, size_t ws_size,
                              hipStream_t stream) {
    const float* nodes   = (const float*)d_in[0];
    const float* W_qk    = (const float*)d_in[1];
    const float* b_qk    = (const float*)d_in[2];
    const float* W_v     = (const float*)d_in[3];
    const float* b_v     = (const float*)d_in[4];
    const float* W_out   = (const float*)d_in[5];
    const float* b_out   = (const float*)d_in[6];
    const int* senders   = (const int*)d_in[7];
    const int* receivers = (const int*)d_in[8];

    const int N = in_sizes[0] / 64;  // 100000
    const int E = in_sizes[7];       // 1000000

    float* out      = (float*)d_out;
    float* attn_out = out + (size_t)N * 64;

    // Workspace: packed fp16 q|v (25.6MB) | rowptr | [spare]
    unsigned char* packed = (unsigned char*)d_ws;
    int* rowp = (int*)(packed + (size_t)N * 256);

    const int PB = (N + 63) / 64;             // proj blocks (1563)
    const int RB = (N + 1 + 255) / 256;       // rowptr blocks
    // 2 launches total: proj is self-contained (weights staged in LDS).
    mhga_proj<<<PB + RB, 256, 0, stream>>>(nodes, W_qk, W_v, b_qk, b_v,
                                           packed, receivers, rowp, N, E, PB);
    // 2048 blocks = 8192 waves = residency cap; EDGE-BALANCED contiguous
    // ranges per wave (straggler fix); MFMA out-projection per super-lap.
    const int NW = 2048 * 4;
    mhga_attn<<<2048, 256, 0, stream>>>(packed, senders, rowp, W_out, b_out,
                                        out, attn_out, N, E, NW);
}

// Round 15
// 179.828 us; speedup vs baseline: 1.0883x; 1.0883x over previous
//
#include <hip/hip_runtime.h>
#include <math.h>

// N=100000 nodes, E=1000000 edges, D_IN=64, D_MODEL=64, H=4 x D=16.
// Packed node layout: per node, 16 chunks of 16 B; chunk c = bytes [16c,16c+16)
//   = { q[4c..4c+3] fp16 (8 B) | v[4c..4c+3] fp16 (8 B) }. Row = 256 B.
//
// FINAL STRUCTURE (= round-13, verified 180.0 us total; r14's edge-balance
// experiment regressed 75->96 us and is reverted):
//   proj: self-contained MFMA projection (weights staged in LDS) + rowptr
//         tail blocks. 2 launches total.
//   attn: persistent 8192 waves, interleaved stride-NW nodes, 2-deep
//         pipelined gathers, in-register+LDS single-pass softmax,
//         once-per-wave MFMA out-projection from Wout directly.

typedef _Float16 h2 __attribute__((ext_vector_type(2)));
typedef _Float16 half8 __attribute__((ext_vector_type(8)));
typedef float floatx4 __attribute__((ext_vector_type(4)));

#define SP_ROW 136  // fp16 per LDS row (272 B): +8 pad breaks pow-2 bank stride
#define SW_ROW 72   // fp16 per sW row (144 B = 9x16: 16-B aligned b128 reads)

// ---------------------------------------------------------------------------
// Kernel 1: MFMA fp16 projection -> packed fp16 q|v rows. Self-contained:
// stages Wqk|Wv transposed-cast into sW (coalesced f32 reads, one
// __syncthreads), then B-frags from LDS. Tail blocks [PB,PB+RB) do the CSR
// rowptr binary search.
__global__ __launch_bounds__(256) void mhga_proj(
    const float* __restrict__ X,
    const float* __restrict__ Wqk, const float* __restrict__ Wv,
    const float* __restrict__ bqk, const float* __restrict__ bv,
    unsigned char* __restrict__ packed,
    const int* __restrict__ receivers, int* __restrict__ row_ptr,
    int N, int E, int PB)
{
    if ((int)blockIdx.x >= PB) {
        const int n = (blockIdx.x - PB) * 256 + threadIdx.x;
        if (n > N) return;
        int lo = 0, hi = E;
        while (lo < hi) {
            const int mid = (lo + hi) >> 1;
            if (receivers[mid] < n) lo = mid + 1; else hi = mid;
        }
        row_ptr[n] = lo;
        return;
    }

    __shared__ __align__(16) _Float16 sP[64 * SP_ROW];   // 17408 B repack tile
    __shared__ __align__(16) _Float16 sW[128 * SW_ROW];  // 18432 B weight tile
    const int t = threadIdx.x;
    const int w = t >> 6, lane = t & 63;
    const int ln = lane & 15, quad = lane >> 4;
    const int m0 = blockIdx.x * 64;

    // Stage sW[m][k] = fp16 of (m<64 ? Wqk[k][m] : Wv[k][m-64]).
    for (int i = t; i < 8192; i += 256) {
        const int hf = i >> 12;          // 0: Wqk, 1: Wv
        const int j = i & 4095;          // j = k*64 + m'
        const int k = j >> 6, mp = j & 63;
        const float wv = hf ? Wv[j] : Wqk[j];
        sW[(hf * 64 + mp) * SW_ROW + k] = (_Float16)wv;
    }

    // A fragments: A[m=ln][k=quad*8+j], k-halves 0 / 32. Direct f32 loads.
    const int arow = min(m0 + w * 16 + ln, N - 1);
    const float* xr = X + (size_t)arow * 64;
    const float4 xa = *(const float4*)(xr + quad * 8);
    const float4 xb = *(const float4*)(xr + quad * 8 + 4);
    const float4 xc = *(const float4*)(xr + 32 + quad * 8);
    const float4 xd = *(const float4*)(xr + 32 + quad * 8 + 4);
    const half8 a0 = { (_Float16)xa.x, (_Float16)xa.y, (_Float16)xa.z,
                       (_Float16)xa.w, (_Float16)xb.x, (_Float16)xb.y,
                       (_Float16)xb.z, (_Float16)xb.w };
    const half8 a1 = { (_Float16)xc.x, (_Float16)xc.y, (_Float16)xc.z,
                       (_Float16)xc.w, (_Float16)xd.x, (_Float16)xd.y,
                       (_Float16)xd.z, (_Float16)xd.w };

    __syncthreads();   // sW visible to all waves

    // 8 output tiles: B[k][n], lane&15 = n-within-tile, k = quad*8+j.
    floatx4 acc[8];
#pragma unroll
    for (int tt = 0; tt < 8; ++tt) {
        const _Float16* wrow = sW + (tt * 16 + ln) * SW_ROW;
        const half8 b0 = *(const half8*)(wrow + quad * 8);
        const half8 b1 = *(const half8*)(wrow + 32 + quad * 8);
        floatx4 c = {0.f, 0.f, 0.f, 0.f};
        c = __builtin_amdgcn_mfma_f32_16x16x32_f16(a0, b0, c, 0, 0, 0);
        c = __builtin_amdgcn_mfma_f32_16x16x32_f16(a1, b1, c, 0, 0, 0);
        acc[tt] = c;
    }

    // Repack: D row = quad*4+reg, col j = tt*16+ln. q col j -> fp16 idx
    // (j>>2)*8 + (j&3); v col j -> (j>>2)*8 + 4 + (j&3).
#pragma unroll
    for (int tt = 0; tt < 8; ++tt) {
        const float bt = (tt < 4) ? bqk[tt * 16 + ln] : bv[(tt - 4) * 16 + ln];
        const int j = (tt & 3) * 16 + ln;
        const int fidx = (j >> 2) * 8 + ((tt < 4) ? 0 : 4) + (j & 3);
#pragma unroll
        for (int r = 0; r < 4; ++r) {
            const int lrow = w * 16 + quad * 4 + r;
            sP[lrow * SP_ROW + fidx] = (_Float16)(acc[tt][r] + bt);
        }
    }

    // Wave-local coalesced copy (no barrier; same-wave in-order DS).
    const int crow = w * 16 + (lane >> 2);
    const int grow = m0 + crow;
    if (grow < N) {
        const _Float16* src = sP + crow * SP_ROW + (lane & 3) * 32;
        unsigned char* dst = packed + (size_t)grow * 256 + (lane & 3) * 64;
#pragma unroll
        for (int c = 0; c < 4; ++c)
            *(uint4*)(dst + c * 16) = *(const uint4*)(src + c * 8);
    }
}

// ---------------------------------------------------------------------------
// Kernel 2: fused attention + once-per-wave MFMA out-projection (verified
// r13 config: attn 75-78 us, bank conflicts 0, VGPR 44).
__global__ __launch_bounds__(256) void mhga_attn(
    const unsigned char* __restrict__ packed,
    const int* __restrict__ senders, const int* __restrict__ row_ptr,
    const float* __restrict__ Wout, const float* __restrict__ bout,
    float* __restrict__ out, float* __restrict__ attn_out,
    int N, int NW)
{
    __shared__ float sAtt[4][256];                    // p stage (4 KB)
    __shared__ __align__(16) _Float16 sC[4][16][76];  // ctx tiles (9728 B)
    const int t = threadIdx.x;
    const int wave = t >> 6, lane = t & 63;
    const int g = lane >> 4, tl = lane & 15;   // edge-group, channel-lane

    const int W = blockIdx.x * 4 + wave;              // global wave id
    const int count = (W < N) ? ((N - W + NW - 1) / NW) : 0;   // <= 13

    for (int i = 0; i < count; ++i) {
        const int n = W + i * NW;                     // interleaved assignment
        const int e0 = row_ptr[n];
        const int e1 = row_ptr[n + 1];
        const int cnt = e1 - e0;

        float l = 0.f;
        float4 ctx = make_float4(0.f, 0.f, 0.f, 0.f);
        const uint2 qpk = *(const uint2*)(packed + (size_t)n * 256 + tl * 16);
        const h2 q0 = __builtin_bit_cast(h2, qpk.x);
        const h2 q1 = __builtin_bit_cast(h2, qpk.y);

        if (cnt <= 64) {
            // ---- hot path: 2-deep pipelined gathers, p staged in LDS ----
            int sid = 0;
            if (e0 + lane < e1) sid = senders[e0 + lane];   // coalesced
            const int iters = (cnt + 3) >> 2;
            const int s0 = __shfl(sid, g, 64);
            uint4 pk = *(const uint4*)(packed + (size_t)s0 * 256 + tl * 16);
            for (int it = 0; it < iters; ++it) {
                uint4 pkn = pk;
                if (it + 1 < iters) {                // wave-uniform branch
                    const int sn = __shfl(sid, (it + 1) * 4 + g, 64);
                    pkn = *(const uint4*)(packed + (size_t)sn * 256 + tl * 16);
                }
                const int idx = it * 4 + g;          // this group's edge
                const h2 k0 = __builtin_bit_cast(h2, pk.x);
                const h2 k1 = __builtin_bit_cast(h2, pk.y);
                const h2 v0 = __builtin_bit_cast(h2, pk.z);
                const h2 v1 = __builtin_bit_cast(h2, pk.w);
                float d = __builtin_amdgcn_fdot2(q0, k0, 0.f, false);
                d = __builtin_amdgcn_fdot2(q1, k1, d, false);
                d += __shfl_xor(d, 1, 64);          // head-group reduce
                d += __shfl_xor(d, 2, 64);
                float p = __expf(d);
                p = (idx < cnt) ? p : 0.f;          // cndmask, no branch
                if ((tl & 3) == 0)
                    sAtt[wave][idx * 4 + (tl >> 2)] = p;   // conflict-free
                l += p;
                ctx.x = fmaf(p, (float)v0.x, ctx.x);
                ctx.y = fmaf(p, (float)v0.y, ctx.y);
                ctx.z = fmaf(p, (float)v1.x, ctx.z);
                ctx.w = fmaf(p, (float)v1.y, ctx.w);
                pk = pkn;
            }
        } else {
            // ---- rare fallback: raw p -> attn_out, normalize in place ----
            for (int base = e0; base < e1; base += 64) {
                const int c2 = min(64, e1 - base);
                int sid2 = 0;
                if (base + lane < e1) sid2 = senders[base + lane];
                const int it2 = (c2 + 3) >> 2;
                for (int ii = 0; ii < it2; ++ii) {
                    const int idx = ii * 4 + g;
                    const int s = __shfl(sid2, idx, 64);
                    if (idx < c2) {
                        const uint4 pk =
                            *(const uint4*)(packed + (size_t)s * 256 + tl * 16);
                        const h2 k0 = __builtin_bit_cast(h2, pk.x);
                        const h2 k1 = __builtin_bit_cast(h2, pk.y);
                        const h2 v0 = __builtin_bit_cast(h2, pk.z);
                        const h2 v1 = __builtin_bit_cast(h2, pk.w);
                        float d = __builtin_amdgcn_fdot2(q0, k0, 0.f, false);
                        d = __builtin_amdgcn_fdot2(q1, k1, d, false);
                        d += __shfl_xor(d, 1, 64);
                        d += __shfl_xor(d, 2, 64);
                        const float p = __expf(d);
                        if ((tl & 3) == 0)
                            attn_out[(size_t)(base + idx) * 4 + (tl >> 2)] = p;
                        l += p;
                        ctx.x = fmaf(p, (float)v0.x, ctx.x);
                        ctx.y = fmaf(p, (float)v0.y, ctx.y);
                        ctx.z = fmaf(p, (float)v1.x, ctx.z);
                        ctx.w = fmaf(p, (float)v1.y, ctx.w);
                    }
                }
            }
        }

        // Sum the 4 edge-group partials (butterfly -> all lanes merged).
#pragma unroll
        for (int mask = 16; mask <= 32; mask <<= 1) {
            l     += __shfl_xor(l, mask, 64);
            ctx.x += __shfl_xor(ctx.x, mask, 64);
            ctx.y += __shfl_xor(ctx.y, mask, 64);
            ctx.z += __shfl_xor(ctx.z, mask, 64);
            ctx.w += __shfl_xor(ctx.w, mask, 64);
        }
        const float inv = (l > 0.f) ? (1.f / l) : 0.f;   // per-head (tl>>2)

        // Pass B: attn = p / l[head], head = f&3 = lane&3 (stride 64).
        const float lh = __shfl(l, (lane & 3) << 2, 64);
        const float invl = (lh > 0.f) ? (1.f / lh) : 0.f;
        if (cnt <= 64) {
            const int cnt4 = cnt * 4;
            for (int f = lane; f < cnt4; f += 64)
                attn_out[e0 * 4 + f] = sAtt[wave][f] * invl;   // wave-local LDS
        } else {
            __builtin_amdgcn_s_waitcnt(0x0F70);   // vmcnt(0): drain raw-p stores
            volatile const float* vp = attn_out;  // L1-bypass
            for (int f = e0 * 4 + lane; f < e1 * 4; f += 64)
                attn_out[f] = vp[f] * invl;
        }

        // Normalized ctx -> fp16 LDS tile row i (g==0 lanes, 16 x 8 B).
        // Head of chans 4tl..4tl+3 is tl>>2, matching this lane's inv.
        if (g == 0) {
            const h2 c01 = { (_Float16)(ctx.x * inv), (_Float16)(ctx.y * inv) };
            const h2 c23 = { (_Float16)(ctx.z * inv), (_Float16)(ctx.w * inv) };
            uint2 pc;
            pc.x = __builtin_bit_cast(unsigned int, c01);
            pc.y = __builtin_bit_cast(unsigned int, c23);
            *(uint2*)(&sC[wave][i][tl * 4]) = pc;
        }
    }

    // ---- once-per-wave MFMA out-projection: rows W + lrow*NW ----
    // A[m=tl][k=g*8+j] from sC (same-wave in-order DS: no barrier needed);
    // rows >= count are garbage but D-rows are independent and unstored.
    // B[k][n] built directly from Wout (L2-hot; 64 scalar loads/lane once
    // per wave; fp16 cast = same rounding as a prep-transposed path).
    const half8 a0 = *(const half8*)(&sC[wave][tl][g * 8]);
    const half8 a1 = *(const half8*)(&sC[wave][tl][32 + g * 8]);
#pragma unroll
    for (int tt = 0; tt < 4; ++tt) {
        half8 b0, b1;
#pragma unroll
        for (int j = 0; j < 8; ++j) {
            b0[j] = (_Float16)Wout[(g * 8 + j) * 64 + tt * 16 + tl];
            b1[j] = (_Float16)Wout[(32 + g * 8 + j) * 64 + tt * 16 + tl];
        }
        floatx4 c = {0.f, 0.f, 0.f, 0.f};
        c = __builtin_amdgcn_mfma_f32_16x16x32_f16(a0, b0, c, 0, 0, 0);
        c = __builtin_amdgcn_mfma_f32_16x16x32_f16(a1, b1, c, 0, 0, 0);
        const float bt = bout[tt * 16 + tl];
#pragma unroll
        for (int r = 0; r < 4; ++r) {
            const int lrow = g * 4 + r;
            if (lrow < count)
                out[(size_t)(W + (size_t)lrow * NW) * 64 + tt * 16 + tl] =
                    c[r] + bt;
        }
    }
}

// ---------------------------------------------------------------------------
extern "C" void kernel_launch(void* const* d_in, const int* in_sizes, int n_in,
                              void* d_out, int out_size, void* d_ws, size_t ws_size,
                              hipStream_t stream) {
    const float* nodes   = (const float*)d_in[0];
    const float* W_qk    = (const float*)d_in[1];
    const float* b_qk    = (const float*)d_in[2];
    const float* W_v     = (const float*)d_in[3];
    const float* b_v     = (const float*)d_in[4];
    const float* W_out   = (const float*)d_in[5];
    const float* b_out   = (const float*)d_in[6];
    const int* senders   = (const int*)d_in[7];
    const int* receivers = (const int*)d_in[8];

    const int N = in_sizes[0] / 64;  // 100000
    const int E = in_sizes[7];       // 1000000

    float* out      = (float*)d_out;
    float* attn_out = out + (size_t)N * 64;

    // Workspace: packed fp16 q|v (25.6MB) | rowptr | [spare]
    unsigned char* packed = (unsigned char*)d_ws;
    int* rowp = (int*)(packed + (size_t)N * 256);

    const int PB = (N + 63) / 64;             // proj blocks (1563)
    const int RB = (N + 1 + 255) / 256;       // rowptr blocks
    // 2 launches total: proj is self-contained (weights staged in LDS).
    mhga_proj<<<PB + RB, 256, 0, stream>>>(nodes, W_qk, W_v, b_qk, b_v,
                                           packed, receivers, rowp, N, E, PB);
    // 2048 blocks = 8192 waves = residency cap; interleaved stride-NW node
    // assignment; max 13 laps/wave; MFMA out-projection once per wave.
    const int NW = 2048 * 4;
    mhga_attn<<<2048, 256, 0, stream>>>(packed, senders, rowp, W_out, b_out,
                                        out, attn_out, N, NW);
}